// Round 2
// baseline (12667.246 us; speedup 1.0000x reference)
//
#include <hip/hip_runtime.h>
#include <hip/hip_bf16.h>

#define SEQ   256
#define BATCH 64
#define HID   1024
#define EMBD  512
#define VOCAB 128
#define G4    4096
#define NWG   256
#define HB_STRIDE (BATCH * HID)   // 65536

typedef short bf16x8_t __attribute__((ext_vector_type(8)));
typedef float f32x4_t  __attribute__((ext_vector_type(4)));
using bf16 = __hip_bfloat16;

// ---------------- casts ----------------
__global__ void cast_f32_bf16(const float* __restrict__ src, bf16* __restrict__ dst, int n) {
    int i = blockIdx.x * blockDim.x + threadIdx.x;
    int stride = gridDim.x * blockDim.x;
    for (; i < n; i += stride) dst[i] = __float2bfloat16(src[i]);
}

// ---------------- init: h/c state + barrier ----------------
__global__ void init_all(const float* __restrict__ h0, const float* __restrict__ c0,
                         bf16* __restrict__ hb0, bf16* __restrict__ hb1,
                         float* __restrict__ cb0, float* __restrict__ cb1,
                         int* __restrict__ bar) {
    if (blockIdx.x == 0 && threadIdx.x < 8) bar[threadIdx.x] = 0;
    int i = blockIdx.x * blockDim.x + threadIdx.x;
    int stride = gridDim.x * blockDim.x;
    for (; i < BATCH * HID; i += stride) {
        hb0[HB_STRIDE + i] = __float2bfloat16(h0[i]);               // parity 1 (read at s=0)
        hb1[i]             = __float2bfloat16(h0[BATCH * HID + i]); // parity 0 (read at s=1)
        cb0[i] = c0[i];
        cb1[i] = c0[BATCH * HID + i];
    }
}

// ---------------- E = emb @ Wih0.T + b0   [VOCAB][G4] f32 ----------------
__global__ __launch_bounds__(256) void emb_gemm(
    const bf16* __restrict__ emb_bf,   // [128][512]
    const bf16* __restrict__ Wih0_bf,  // [4096][512]
    const float* __restrict__ b0,
    float* __restrict__ E)             // [128][4096]
{
    __shared__ float pb[4 * 128 * 17];
    const int tid = threadIdx.x, l = tid & 63, w = tid >> 6;
    const int lm = l & 15, k8 = (l >> 4) << 3;
    const int colbase = blockIdx.x * 16;
    const int gcol = colbase + lm;
    const int kq = w * 128;

    f32x4_t acc[8];
    #pragma unroll
    for (int rt = 0; rt < 8; ++rt) acc[rt] = f32x4_t{0.f, 0.f, 0.f, 0.f};

    bf16x8_t bf[4];
    #pragma unroll
    for (int k = 0; k < 4; ++k)
        bf[k] = *reinterpret_cast<const bf16x8_t*>(Wih0_bf + gcol * EMBD + kq + k * 32 + k8);

    #pragma unroll
    for (int k = 0; k < 4; ++k)
        #pragma unroll
        for (int rt = 0; rt < 8; ++rt) {
            bf16x8_t a = *reinterpret_cast<const bf16x8_t*>(
                emb_bf + (rt * 16 + lm) * EMBD + kq + k * 32 + k8);
            acc[rt] = __builtin_amdgcn_mfma_f32_16x16x32_bf16(a, bf[k], acc[rt], 0, 0, 0);
        }

    const int r0 = (l >> 4) << 2;
    #pragma unroll
    for (int rt = 0; rt < 8; ++rt)
        #pragma unroll
        for (int r = 0; r < 4; ++r)
            pb[(w * 128 + rt * 16 + r0 + r) * 17 + lm] = acc[rt][r];
    __syncthreads();

    #pragma unroll
    for (int i = 0; i < 8; ++i) {
        int p = tid + i * 256;           // [0, 2048)
        int m = p >> 4, cc = p & 15;
        float g = pb[(0 * 128 + m) * 17 + cc] + pb[(1 * 128 + m) * 17 + cc]
                + pb[(2 * 128 + m) * 17 + cc] + pb[(3 * 128 + m) * 17 + cc];
        E[m * G4 + colbase + cc] = g + b0[colbase + cc];
    }
}

// ---------------- grid barrier (sense-reversing, device scope) ----------------
__device__ __forceinline__ void gridbar(int* bar, int tid) {
    __syncthreads();
    if (tid == 0) {
        __threadfence();   // release prior global writes
        int g0 = __hip_atomic_load(bar + 1, __ATOMIC_RELAXED, __HIP_MEMORY_SCOPE_AGENT);
        int my = __hip_atomic_fetch_add(bar, 1, __ATOMIC_ACQ_REL, __HIP_MEMORY_SCOPE_AGENT);
        if (my == NWG - 1) {
            __hip_atomic_store(bar, 0, __ATOMIC_RELAXED, __HIP_MEMORY_SCOPE_AGENT);
            __hip_atomic_fetch_add(bar + 1, 1, __ATOMIC_RELEASE, __HIP_MEMORY_SCOPE_AGENT);
        } else {
            while (__hip_atomic_load(bar + 1, __ATOMIC_ACQUIRE, __HIP_MEMORY_SCOPE_AGENT) == g0)
                __builtin_amdgcn_s_sleep(2);
        }
        __threadfence();   // acquire
    }
    __syncthreads();
}

// ---------------- per-step MFMA block (A from global, B in regs) ----------------
template<int NKI>
__device__ __forceinline__ void mfma_block(const bf16* __restrict__ asrc,
    const bf16x8_t (&Breg)[2 * NKI], f32x4_t (&acc)[2][4], int lm, int k8)
{
    constexpr int NCH = NKI / 4;
    bf16x8_t a[2][4][4];
    #pragma unroll
    for (int k = 0; k < 4; ++k)
        #pragma unroll
        for (int rt = 0; rt < 4; ++rt)
            a[0][k][rt] = *reinterpret_cast<const bf16x8_t*>(
                asrc + (rt * 16 + lm) * HID + k * 32 + k8);
    #pragma unroll
    for (int c = 0; c < NCH; ++c) {
        if (c + 1 < NCH) {
            #pragma unroll
            for (int k = 0; k < 4; ++k)
                #pragma unroll
                for (int rt = 0; rt < 4; ++rt)
                    a[(c + 1) & 1][k][rt] = *reinterpret_cast<const bf16x8_t*>(
                        asrc + (rt * 16 + lm) * HID + ((c + 1) * 4 + k) * 32 + k8);
        }
        #pragma unroll
        for (int k = 0; k < 4; ++k)
            #pragma unroll
            for (int rt = 0; rt < 4; ++rt)
                #pragma unroll
                for (int ct = 0; ct < 2; ++ct)
                    acc[ct][rt] = __builtin_amdgcn_mfma_f32_16x16x32_bf16(
                        a[c & 1][k][rt], Breg[ct * NKI + c * 4 + k], acc[ct][rt], 0, 0, 0);
    }
}

// ---------------- persistent two-layer pipelined LSTM ----------------
template<int LAYER, int NKI>
__device__ __forceinline__ void run_layer(
    const int* __restrict__ x,
    const bf16* __restrict__ Whh, const bf16* __restrict__ Wx,
    const float* __restrict__ E, const float* __restrict__ b1,
    bf16* __restrict__ hb_self, const bf16* __restrict__ hb_other,
    float* __restrict__ cbuf, float* __restrict__ hm,
    int* __restrict__ bar, float* __restrict__ pbf,
    int tid, int wg)
{
    const int l = tid & 63, w = tid >> 6;
    const int lm = l & 15, k8 = (l >> 4) << 3;
    const int hbase = (wg & 127) * 8;
    const int c1 = 16 + lm;
    const int gcolA = (lm >> 3) * HID + hbase + (lm & 7);
    const int gcolB = (c1 >> 3) * HID + hbase + (c1 & 7);

    int kq;
    const bf16* Wsrc;
    if (LAYER == 0) { kq = w * 256; Wsrc = Whh; }
    else            { kq = (w & 1) * 512; Wsrc = (w < 2) ? Whh : Wx; }

    // one-time weight preload into VGPRs
    bf16x8_t Breg[2 * NKI];
    #pragma unroll
    for (int kk = 0; kk < NKI; ++kk) {
        Breg[kk]       = *reinterpret_cast<const bf16x8_t*>(Wsrc + gcolA * HID + kq + kk * 32 + k8);
        Breg[NKI + kk] = *reinterpret_cast<const bf16x8_t*>(Wsrc + gcolB * HID + kq + kk * 32 + k8);
    }

    for (int s = 0; s < SEQ + 1; ++s) {
        const bool active = (LAYER == 0) ? (s < SEQ) : (s >= 1);
        if (active) {
            const int pprev = (s - 1) & 1;
            const bf16* asrc;
            if (LAYER == 0) asrc = hb_self + pprev * HB_STRIDE + kq;
            else            asrc = ((w < 2) ? hb_self : hb_other) + pprev * HB_STRIDE + kq;

            f32x4_t acc[2][4];
            #pragma unroll
            for (int ct = 0; ct < 2; ++ct)
                #pragma unroll
                for (int rt = 0; rt < 4; ++rt) acc[ct][rt] = f32x4_t{0.f, 0.f, 0.f, 0.f};

            mfma_block<NKI>(asrc, Breg, acc, lm, k8);

            const int r0 = (l >> 4) << 2;
            #pragma unroll
            for (int ct = 0; ct < 2; ++ct)
                #pragma unroll
                for (int rt = 0; rt < 4; ++rt)
                    #pragma unroll
                    for (int r = 0; r < 4; ++r)
                        pbf[(w * 64 + rt * 16 + r0 + r) * 88 + ct * 16 + lm] = acc[ct][rt][r];
        }
        __syncthreads();
        if (active) {
            const int t   = (LAYER == 0) ? s : s - 1;
            const int wrp = s & 1;
            #pragma unroll
            for (int i = 0; i < 2; ++i) {
                const int p = tid + i * 256;
                const int m = p >> 3, hh = p & 7, col = hbase + hh;
                float g[4];
                #pragma unroll
                for (int sec = 0; sec < 4; ++sec) {
                    const int ciw = sec * 8 + hh;
                    g[sec] = pbf[(0 * 64 + m) * 88 + ciw] + pbf[(1 * 64 + m) * 88 + ciw]
                           + pbf[(2 * 64 + m) * 88 + ciw] + pbf[(3 * 64 + m) * 88 + ciw];
                }
                if (LAYER == 0) {
                    const int xv = x[t * BATCH + m];
                    #pragma unroll
                    for (int sec = 0; sec < 4; ++sec) g[sec] += E[xv * G4 + sec * HID + col];
                } else {
                    #pragma unroll
                    for (int sec = 0; sec < 4; ++sec) g[sec] += b1[sec * HID + col];
                }
                float si = 1.f / (1.f + expf(-g[0]));
                float sf = 1.f / (1.f + expf(-g[1]));
                float tg = tanhf(g[2]);
                float so = 1.f / (1.f + expf(-g[3]));
                const int idx = m * HID + col;
                float cn = sf * cbuf[idx] + si * tg;
                float hn = so * tanhf(cn);
                cbuf[idx] = cn;
                hb_self[wrp * HB_STRIDE + idx] = __float2bfloat16(hn);
                if ((LAYER == 0 && s == SEQ - 1) || (LAYER == 1 && s == SEQ)) hm[idx] = hn;
            }
        }
        gridbar(bar, tid);
    }
}

__global__ __launch_bounds__(256, 1) void lstm_persist(
    const int* __restrict__ x,
    const bf16* __restrict__ Whh0, const bf16* __restrict__ Whh1,
    const bf16* __restrict__ Wih1,
    const float* __restrict__ E, const float* __restrict__ b1,
    bf16* __restrict__ hb0, bf16* __restrict__ hb1,
    float* __restrict__ cb0, float* __restrict__ cb1,
    float* __restrict__ hm0, float* __restrict__ hm1,
    int* __restrict__ bar)
{
    __shared__ float pbf[4 * 64 * 88];   // 90 KB -> forces 1 WG/CU
    const int tid = threadIdx.x, wg = blockIdx.x;
    if (wg < 128)
        run_layer<0, 8>(x, Whh0, nullptr, E, nullptr, hb0, nullptr, cb0, hm0, bar, pbf, tid, wg);
    else
        run_layer<1, 16>(x, Whh1, Wih1, nullptr, b1, hb1, hb0, cb1, hm1, bar, pbf, tid, wg);
}

// ---------------- FC head + output copy ----------------
__global__ void logits_kernel(const float* __restrict__ h, const float* __restrict__ Wfc,
                              const float* __restrict__ bfc, float* __restrict__ out) {
    int t = blockIdx.x * blockDim.x + threadIdx.x;
    if (t >= BATCH * VOCAB) return;
    int m = t >> 7, v = t & 127;
    const float4* hp = reinterpret_cast<const float4*>(h + (size_t)m * HID);
    const float4* wp = reinterpret_cast<const float4*>(Wfc + (size_t)v * HID);
    float acc = 0.f;
    #pragma unroll 4
    for (int k = 0; k < HID / 4; ++k) {
        float4 a = hp[k], w = wp[k];
        acc += a.x * w.x + a.y * w.y + a.z * w.z + a.w * w.w;
    }
    out[t] = acc + bfc[v];
}

__global__ void copy_out(const float* __restrict__ hm0, const float* __restrict__ hm1,
                         const float* __restrict__ cb0, const float* __restrict__ cb1,
                         float* __restrict__ out) {
    const int n = BATCH * HID;
    int i = blockIdx.x * blockDim.x + threadIdx.x;
    int stride = gridDim.x * blockDim.x;
    for (; i < n; i += stride) {
        out[BATCH * VOCAB + i]         = hm0[i];
        out[BATCH * VOCAB + n + i]     = hm1[i];
        out[BATCH * VOCAB + 2 * n + i] = cb0[i];
        out[BATCH * VOCAB + 3 * n + i] = cb1[i];
    }
}

// ---------------- launch ----------------
extern "C" void kernel_launch(void* const* d_in, const int* in_sizes, int n_in,
                              void* d_out, int out_size, void* d_ws, size_t ws_size,
                              hipStream_t stream) {
    const int*   x    = (const int*)d_in[0];
    const float* h0   = (const float*)d_in[1];
    const float* c0   = (const float*)d_in[2];
    const float* emb  = (const float*)d_in[3];
    const float* Wih0 = (const float*)d_in[4];
    const float* Whh0 = (const float*)d_in[5];
    const float* b0   = (const float*)d_in[6];
    const float* Wih1 = (const float*)d_in[7];
    const float* Whh1 = (const float*)d_in[8];
    const float* b1   = (const float*)d_in[9];
    const float* Wfc  = (const float*)d_in[10];
    const float* bfc  = (const float*)d_in[11];
    float* out = (float*)d_out;

    char* ws = (char*)d_ws;
    size_t off = 0;
    auto alloc = [&](size_t bytes) -> void* {
        void* p = ws + off;
        off += (bytes + 255) & ~(size_t)255;
        return p;
    };
    bf16* emb_bf  = (bf16*)alloc((size_t)VOCAB * EMBD * 2);
    bf16* Wih0_bf = (bf16*)alloc((size_t)G4 * EMBD * 2);
    bf16* Whh0_bf = (bf16*)alloc((size_t)G4 * HID * 2);
    bf16* Wih1_bf = (bf16*)alloc((size_t)G4 * HID * 2);
    bf16* Whh1_bf = (bf16*)alloc((size_t)G4 * HID * 2);
    float* E      = (float*)alloc((size_t)VOCAB * G4 * 4);
    bf16* hb0     = (bf16*)alloc((size_t)2 * HB_STRIDE * 2);
    bf16* hb1     = (bf16*)alloc((size_t)2 * HB_STRIDE * 2);
    float* cb0    = (float*)alloc((size_t)HB_STRIDE * 4);
    float* cb1    = (float*)alloc((size_t)HB_STRIDE * 4);
    float* hm0    = (float*)alloc((size_t)HB_STRIDE * 4);
    float* hm1    = (float*)alloc((size_t)HB_STRIDE * 4);
    int*   bar    = (int*)alloc(256);
    (void)ws_size; (void)in_sizes; (void)n_in; (void)out_size;

    cast_f32_bf16<<<64,  256, 0, stream>>>(emb,  emb_bf,  VOCAB * EMBD);
    cast_f32_bf16<<<512, 256, 0, stream>>>(Wih0, Wih0_bf, G4 * EMBD);
    cast_f32_bf16<<<512, 256, 0, stream>>>(Whh0, Whh0_bf, G4 * HID);
    cast_f32_bf16<<<512, 256, 0, stream>>>(Wih1, Wih1_bf, G4 * HID);
    cast_f32_bf16<<<512, 256, 0, stream>>>(Whh1, Whh1_bf, G4 * HID);
    init_all<<<64, 256, 0, stream>>>(h0, c0, hb0, hb1, cb0, cb1, bar);
    emb_gemm<<<G4 / 16, 256, 0, stream>>>(emb_bf, Wih0_bf, b0, E);

    lstm_persist<<<NWG, 256, 0, stream>>>(x, Whh0_bf, Whh1_bf, Wih1_bf, E, b1,
                                          hb0, hb1, cb0, cb1, hm0, hm1, bar);

    logits_kernel<<<(BATCH * VOCAB + 255) / 256, 256, 0, stream>>>(hm1, Wfc, bfc, out);
    copy_out<<<256, 256, 0, stream>>>(hm0, hm1, cb0, cb1, out);
}

// Round 3
// 3796.088 us; speedup vs baseline: 3.3369x; 3.3369x over previous
//
#include <hip/hip_runtime.h>
#include <hip/hip_bf16.h>

#define SEQ   256
#define BATCH 64
#define HID   1024
#define EMBD  512
#define VOCAB 128
#define G4    4096
#define HBS   (BATCH * HID)      // 65536 elems
#define NWGS  96
#define CNTS  64                 // unsigned stride between counters

typedef short bf16x8_t __attribute__((ext_vector_type(8)));
typedef float f32x4_t  __attribute__((ext_vector_type(4)));
using bf16 = __hip_bfloat16;

// ---------------- device-coherent 16B load (bypasses L1/L2, reads at MALL) ----
__device__ __forceinline__ bf16x8_t cload16(const void* p) {
    bf16x8_t r;
    asm volatile("global_load_dwordx4 %0, %1, off sc0 sc1"
                 : "=v"(r) : "v"(p) : "memory");
    return r;
}

__device__ __forceinline__ float sigm(float v) { return 1.f / (1.f + expf(-v)); }

// ---------------- casts ----------------
__global__ void cast_f32_bf16(const float* __restrict__ src, bf16* __restrict__ dst, int n) {
    int i = blockIdx.x * blockDim.x + threadIdx.x;
    int stride = gridDim.x * blockDim.x;
    for (; i < n; i += stride) dst[i] = __float2bfloat16(src[i]);
}

// ---------------- init: h parities + counters ----------------
__global__ void init_all(const float* __restrict__ h0,
                         bf16* __restrict__ hb0, bf16* __restrict__ hb1,
                         unsigned* __restrict__ cnt) {
    int i = blockIdx.x * blockDim.x + threadIdx.x;
    if (i < 8 * CNTS) cnt[i] = 0u;
    int stride = gridDim.x * blockDim.x;
    for (int k = i; k < HBS; k += stride) {
        hb0[HBS + k] = __float2bfloat16(h0[k]);        // parity 1
        hb1[HBS + k] = __float2bfloat16(h0[HBS + k]);  // parity 1
    }
}

// ---------------- E = emb @ Wih0.T + b0   [VOCAB][G4] f32 (validated r2) -----
__global__ __launch_bounds__(256) void emb_gemm(
    const bf16* __restrict__ emb_bf, const bf16* __restrict__ Wih0_bf,
    const float* __restrict__ b0, float* __restrict__ E) {
    __shared__ float pb[4 * 128 * 17];
    const int tid = threadIdx.x, l = tid & 63, w = tid >> 6;
    const int lm = l & 15, k8 = (l >> 4) << 3;
    const int colbase = blockIdx.x * 16;
    const int gcol = colbase + lm;
    const int kq = w * 128;

    f32x4_t acc[8];
    #pragma unroll
    for (int rt = 0; rt < 8; ++rt) acc[rt] = f32x4_t{0.f, 0.f, 0.f, 0.f};
    bf16x8_t bf[4];
    #pragma unroll
    for (int k = 0; k < 4; ++k)
        bf[k] = *reinterpret_cast<const bf16x8_t*>(Wih0_bf + gcol * EMBD + kq + k * 32 + k8);
    #pragma unroll
    for (int k = 0; k < 4; ++k)
        #pragma unroll
        for (int rt = 0; rt < 8; ++rt) {
            bf16x8_t a = *reinterpret_cast<const bf16x8_t*>(
                emb_bf + (rt * 16 + lm) * EMBD + kq + k * 32 + k8);
            acc[rt] = __builtin_amdgcn_mfma_f32_16x16x32_bf16(a, bf[k], acc[rt], 0, 0, 0);
        }
    const int r0 = (l >> 4) << 2;
    #pragma unroll
    for (int rt = 0; rt < 8; ++rt)
        #pragma unroll
        for (int r = 0; r < 4; ++r)
            pb[(w * 128 + rt * 16 + r0 + r) * 17 + lm] = acc[rt][r];
    __syncthreads();
    #pragma unroll
    for (int i = 0; i < 8; ++i) {
        int p = tid + i * 256;
        int m = p >> 4, cc = p & 15;
        float g = pb[(0 * 128 + m) * 17 + cc] + pb[(1 * 128 + m) * 17 + cc]
                + pb[(2 * 128 + m) * 17 + cc] + pb[(3 * 128 + m) * 17 + cc];
        E[m * G4 + colbase + cc] = g + b0[colbase + cc];
    }
}

// ---------------- fence-free grid barrier (8 split counters, relaxed) --------
__device__ __forceinline__ void gridbar(unsigned* cnt, int s, int tid, int wg) {
    asm volatile("s_waitcnt vmcnt(0)" ::: "memory");
    __syncthreads();
    if (tid == 0) {
        __hip_atomic_fetch_add(cnt + (wg & 7) * CNTS, 1u,
                               __ATOMIC_RELAXED, __HIP_MEMORY_SCOPE_AGENT);
        const unsigned target = (unsigned)(s + 1) * (NWGS / 8);
        for (;;) {
            unsigned mn = 0xffffffffu;
            #pragma unroll
            for (int i = 0; i < 8; ++i) {
                unsigned v = __hip_atomic_load(cnt + i * CNTS,
                                               __ATOMIC_RELAXED, __HIP_MEMORY_SCOPE_AGENT);
                mn = v < mn ? v : mn;
            }
            if (mn >= target) break;
            __builtin_amdgcn_s_sleep(4);
        }
    }
    __syncthreads();
}

// ---------------- persistent 3-group pipelined LSTM --------------------------
// grp 0 (wg 0-31):  layer0 h-GEMM + act, step t = s       (s in [0,255])
// grp 1 (wg 32-63): layer1 x-GEMM -> xg,  step t = s-1    (s in [1,256])
// grp 2 (wg 64-95): layer1 h-GEMM + act,  step t = s-2    (s in [2,257])
__global__ __launch_bounds__(512, 2) void lstm_persist(
    const int* __restrict__ x,
    const bf16* __restrict__ Whh0, const bf16* __restrict__ Wih1,
    const bf16* __restrict__ Whh1,
    const float* __restrict__ E, const float* __restrict__ b1,
    const float* __restrict__ c0,
    bf16* __restrict__ hb0, bf16* __restrict__ hb1,
    float* __restrict__ xg, unsigned* __restrict__ cnt,
    float* __restrict__ out) {

    __shared__ bf16  Abuf[64 * 512];          // 64 KB: K-half of A, XOR-swizzled
    __shared__ float pbf[2 * 128 * 68];       // 68 KB: 2 slots, col-major [lc][m]

    const int tid = threadIdx.x;
    const int wg  = blockIdx.x;
    const int grp = wg >> 5;
    const int gl  = wg & 31;
    const int colb = gl * 32;

    const int l  = tid & 63, w = tid >> 6;
    const int lm = l & 15, lk = l >> 4;
    const int ch = w & 1, kg = w >> 1;        // col-half, K-group (256 wide)

    const bf16* W = (grp == 0) ? Whh0 : (grp == 1) ? Wih1 : Whh1;

    // weight fragment preload: 64 cols x 256 K per wave = 128 VGPR
    int gcol[4];
    #pragma unroll
    for (int nt = 0; nt < 4; ++nt) {
        int lc = ch * 64 + nt * 16 + lm;
        gcol[nt] = (lc >> 5) * HID + colb + (lc & 31);
    }
    bf16x8_t Breg[4][8];
    #pragma unroll
    for (int nt = 0; nt < 4; ++nt)
        #pragma unroll
        for (int kt = 0; kt < 8; ++kt)
            Breg[nt][kt] = *reinterpret_cast<const bf16x8_t*>(
                W + (size_t)gcol[nt] * HID + kg * 256 + kt * 32 + lk * 8);

    // activation-phase mapping: thread -> (hh, 4 consecutive m)
    const int hh = tid >> 4;                  // 0..31 (h-col within WG)
    const int mq = tid & 15;                  // m = mq*4 + j

    float creg[4];
    if (grp != 1) {
        const float* c0l = c0 + (grp == 2 ? HBS : 0);
        #pragma unroll
        for (int j = 0; j < 4; ++j)
            creg[j] = c0l[(mq * 4 + j) * HID + colb + hh];
    }

    for (int s = 0; s < SEQ + 2; ++s) {
        const bool active = (grp == 0) ? (s < SEQ)
                          : (grp == 1) ? (s >= 1 && s <= SEQ)
                                       : (s >= 2);
        if (active) {
            const int par_r = (s - 1) & 1, par_w = s & 1;
            const bf16* asrc = ((grp == 2) ? hb1 : hb0) + par_r * HBS;

            f32x4_t acc[4][4];

            #pragma unroll
            for (int hk = 0; hk < 2; ++hk) {
                // ---- stage K-half hk of A (coherent 16B loads -> LDS) ----
                bf16x8_t v[8];
                #pragma unroll
                for (int i = 0; i < 8; ++i) {
                    int cid = tid + i * 512;
                    int row = cid >> 6, k16 = cid & 63;
                    v[i] = cload16(asrc + row * HID + hk * 512 + k16 * 8);
                }
                asm volatile("s_waitcnt vmcnt(0)" ::: "memory");
                __builtin_amdgcn_sched_barrier(0);
                #pragma unroll
                for (int i = 0; i < 8; ++i) {
                    int cid = tid + i * 512;
                    int row = cid >> 6, k16 = cid & 63;
                    int sw = (k16 * 8) ^ ((row & 7) << 3);
                    *reinterpret_cast<bf16x8_t*>(Abuf + row * 512 + sw) = v[i];
                }
                __syncthreads();

                // ---- MFMA for waves whose K-slice lives in this half ----
                if ((kg >> 1) == hk) {
                    #pragma unroll
                    for (int mt = 0; mt < 4; ++mt)
                        #pragma unroll
                        for (int nt = 0; nt < 4; ++nt)
                            acc[mt][nt] = f32x4_t{0.f, 0.f, 0.f, 0.f};
                    #pragma unroll
                    for (int kt = 0; kt < 8; ++kt) {
                        const int koff = (kg & 1) * 256 + kt * 32 + lk * 8;
                        bf16x8_t a[4];
                        #pragma unroll
                        for (int mt = 0; mt < 4; ++mt) {
                            int row = mt * 16 + lm;
                            a[mt] = *reinterpret_cast<const bf16x8_t*>(
                                Abuf + row * 512 + (koff ^ ((row & 7) << 3)));
                        }
                        #pragma unroll
                        for (int mt = 0; mt < 4; ++mt)
                            #pragma unroll
                            for (int nt = 0; nt < 4; ++nt)
                                acc[mt][nt] = __builtin_amdgcn_mfma_f32_16x16x32_bf16(
                                    a[mt], Breg[nt][kt], acc[mt][nt], 0, 0, 0);
                    }
                    // partials -> pbf slot (kg&1); half1 waves accumulate
                    float* base = pbf + (kg & 1) * (128 * 68);
                    #pragma unroll
                    for (int mt = 0; mt < 4; ++mt)
                        #pragma unroll
                        for (int nt = 0; nt < 4; ++nt) {
                            int lc = ch * 64 + nt * 16 + lm;
                            float* p = base + lc * 68 + mt * 16 + lk * 4;
                            if (hk == 0) *reinterpret_cast<f32x4_t*>(p) = acc[mt][nt];
                            else *reinterpret_cast<f32x4_t*>(p) =
                                     *reinterpret_cast<const f32x4_t*>(p) + acc[mt][nt];
                        }
                }
                __syncthreads();
            }

            // ---- gate assembly + activation ----
            float g[4][4];
            #pragma unroll
            for (int sec = 0; sec < 4; ++sec) {
                int lc = sec * 32 + hh;
                f32x4_t v0 = *reinterpret_cast<const f32x4_t*>(pbf + lc * 68 + mq * 4);
                f32x4_t v1 = *reinterpret_cast<const f32x4_t*>(pbf + 128 * 68 + lc * 68 + mq * 4);
                #pragma unroll
                for (int j = 0; j < 4; ++j) g[sec][j] = v0[j] + v1[j];
            }

            if (grp == 0) {
                const int t = s;
                #pragma unroll
                for (int j = 0; j < 4; ++j) {
                    int xv = x[t * BATCH + mq * 4 + j];
                    #pragma unroll
                    for (int sec = 0; sec < 4; ++sec)
                        g[sec][j] += E[(size_t)xv * G4 + sec * HID + colb + hh];
                }
            } else if (grp == 1) {
                #pragma unroll
                for (int sec = 0; sec < 4; ++sec) {
                    float bb = b1[sec * HID + colb + hh];
                    #pragma unroll
                    for (int j = 0; j < 4; ++j) g[sec][j] += bb;
                }
                float* xd = xg + (size_t)par_w * BATCH * G4;
                #pragma unroll
                for (int j = 0; j < 4; ++j) {
                    int m = mq * 4 + j;
                    #pragma unroll
                    for (int sec = 0; sec < 4; ++sec)
                        __hip_atomic_store(xd + (size_t)m * G4 + sec * HID + colb + hh,
                                           g[sec][j], __ATOMIC_RELAXED, __HIP_MEMORY_SCOPE_AGENT);
                }
            } else {
                const float* xs = xg + (size_t)par_r * BATCH * G4;
                #pragma unroll
                for (int j = 0; j < 4; ++j) {
                    int m = mq * 4 + j;
                    #pragma unroll
                    for (int sec = 0; sec < 4; ++sec)
                        g[sec][j] += __hip_atomic_load(xs + (size_t)m * G4 + sec * HID + colb + hh,
                                                       __ATOMIC_RELAXED, __HIP_MEMORY_SCOPE_AGENT);
                }
            }

            if (grp != 1) {
                bf16* hdst = ((grp == 0) ? hb0 : hb1) + par_w * HBS;
                const bool last = (grp == 0 && s == SEQ - 1) || (grp == 2 && s == SEQ + 1);
                float* oh = out + BATCH * VOCAB + (grp == 0 ? 0 : HBS);
                float* oc = out + BATCH * VOCAB + 2 * HBS + (grp == 0 ? 0 : HBS);
                #pragma unroll
                for (int j = 0; j < 4; ++j) {
                    float si = sigm(g[0][j]);
                    float sf = sigm(g[1][j]);
                    float tg = tanhf(g[2][j]);
                    float so = sigm(g[3][j]);
                    float cn = sf * creg[j] + si * tg;
                    float hn = so * tanhf(cn);
                    creg[j] = cn;
                    const int idx = (mq * 4 + j) * HID + colb + hh;
                    unsigned short hu = __builtin_bit_cast(unsigned short, __float2bfloat16(hn));
                    __hip_atomic_store((unsigned short*)(hdst + idx), hu,
                                       __ATOMIC_RELAXED, __HIP_MEMORY_SCOPE_AGENT);
                    if (last) { oh[idx] = hn; oc[idx] = cn; }
                }
            }
        }
        gridbar(cnt, s, tid, wg);
    }
}

// ---------------- FC head ----------------
__global__ void logits_kernel(const float* __restrict__ h, const float* __restrict__ Wfc,
                              const float* __restrict__ bfc, float* __restrict__ out) {
    int t = blockIdx.x * blockDim.x + threadIdx.x;
    if (t >= BATCH * VOCAB) return;
    int m = t >> 7, v = t & 127;
    const float4* hp = reinterpret_cast<const float4*>(h + (size_t)m * HID);
    const float4* wp = reinterpret_cast<const float4*>(Wfc + (size_t)v * HID);
    float acc = 0.f;
    #pragma unroll 4
    for (int k = 0; k < HID / 4; ++k) {
        float4 a = hp[k], w = wp[k];
        acc += a.x * w.x + a.y * w.y + a.z * w.z + a.w * w.w;
    }
    out[t] = acc + bfc[v];
}

// ---------------- launch ----------------
extern "C" void kernel_launch(void* const* d_in, const int* in_sizes, int n_in,
                              void* d_out, int out_size, void* d_ws, size_t ws_size,
                              hipStream_t stream) {
    const int*   x    = (const int*)d_in[0];
    const float* h0   = (const float*)d_in[1];
    const float* c0   = (const float*)d_in[2];
    const float* emb  = (const float*)d_in[3];
    const float* Wih0 = (const float*)d_in[4];
    const float* Whh0 = (const float*)d_in[5];
    const float* b0   = (const float*)d_in[6];
    const float* Wih1 = (const float*)d_in[7];
    const float* Whh1 = (const float*)d_in[8];
    const float* b1   = (const float*)d_in[9];
    const float* Wfc  = (const float*)d_in[10];
    const float* bfc  = (const float*)d_in[11];
    float* out = (float*)d_out;

    char* ws = (char*)d_ws;
    size_t off = 0;
    auto alloc = [&](size_t bytes) -> void* {
        void* p = ws + off;
        off += (bytes + 255) & ~(size_t)255;
        return p;
    };
    bf16*  emb_bf  = (bf16*)alloc((size_t)VOCAB * EMBD * 2);
    bf16*  Wih0_bf = (bf16*)alloc((size_t)G4 * EMBD * 2);
    bf16*  Whh0_bf = (bf16*)alloc((size_t)G4 * HID * 2);
    bf16*  Wih1_bf = (bf16*)alloc((size_t)G4 * HID * 2);
    bf16*  Whh1_bf = (bf16*)alloc((size_t)G4 * HID * 2);
    float* E       = (float*)alloc((size_t)VOCAB * G4 * 4);
    bf16*  hb0     = (bf16*)alloc((size_t)2 * HBS * 2);
    bf16*  hb1     = (bf16*)alloc((size_t)2 * HBS * 2);
    float* xg      = (float*)alloc((size_t)2 * BATCH * G4 * 4);
    unsigned* cnt  = (unsigned*)alloc(8 * CNTS * 4);
    (void)ws_size; (void)in_sizes; (void)n_in; (void)out_size;

    cast_f32_bf16<<<64,  256, 0, stream>>>(emb,  emb_bf,  VOCAB * EMBD);
    cast_f32_bf16<<<512, 256, 0, stream>>>(Wih0, Wih0_bf, G4 * EMBD);
    cast_f32_bf16<<<512, 256, 0, stream>>>(Whh0, Whh0_bf, G4 * HID);
    cast_f32_bf16<<<512, 256, 0, stream>>>(Wih1, Wih1_bf, G4 * HID);
    cast_f32_bf16<<<512, 256, 0, stream>>>(Whh1, Whh1_bf, G4 * HID);
    init_all<<<64, 256, 0, stream>>>(h0, hb0, hb1, cnt);
    emb_gemm<<<G4 / 16, 256, 0, stream>>>(emb_bf, Wih0_bf, b0, E);

    lstm_persist<<<NWGS, 512, 0, stream>>>(x, Whh0_bf, Wih1_bf, Whh1_bf,
                                           E, b1, c0, hb0, hb1, xg, cnt, out);

    logits_kernel<<<(BATCH * VOCAB + 255) / 256, 256, 0, stream>>>(
        out + BATCH * VOCAB + HBS, Wfc, bfc, out);
}

// Round 4
// 2848.189 us; speedup vs baseline: 4.4475x; 1.3328x over previous
//
#include <hip/hip_runtime.h>
#include <hip/hip_bf16.h>

#define SEQ   256
#define BATCH 64
#define HID   1024
#define EMBD  512
#define VOCAB 128
#define G4    4096
#define HBS   (BATCH * HID)      // 65536 elems per ring slot (128 KB bf16)
#define CNTS  32                 // uints between counters (128 B spacing)

typedef short bf16x8_t __attribute__((ext_vector_type(8)));
typedef float f32x4_t  __attribute__((ext_vector_type(4)));
using bf16 = __hip_bfloat16;

__device__ __forceinline__ float sigm(float v) { return 1.f / (1.f + expf(-v)); }

// write-through 4B store (visible at MALL; readers use normal cached loads —
// safe because every ring address is written exactly once per launch)
__device__ __forceinline__ void cstore4(void* p, unsigned d) {
    asm volatile("global_store_dword %0, %1, off sc0 sc1" :: "v"(p), "v"(d) : "memory");
}

// ---------------- casts ----------------
__global__ void cast_f32_bf16(const float* __restrict__ src, bf16* __restrict__ dst, int n) {
    int i = blockIdx.x * blockDim.x + threadIdx.x;
    int stride = gridDim.x * blockDim.x;
    for (; i < n; i += stride) dst[i] = __float2bfloat16(src[i]);
}

// ---------------- init: ring slot 0 + counters ----------------
__global__ void init_all(const float* __restrict__ h0,
                         bf16* __restrict__ r0, bf16* __restrict__ r1,
                         unsigned* __restrict__ cnt) {
    int i = blockIdx.x * blockDim.x + threadIdx.x;
    if (i < 16 * CNTS) cnt[i] = 0u;
    int stride = gridDim.x * blockDim.x;
    for (int k = i; k < HBS; k += stride) {
        r0[k] = __float2bfloat16(h0[k]);
        r1[k] = __float2bfloat16(h0[HBS + k]);
    }
}

// ---------------- E = emb @ Wih0.T + b0   [VOCAB][G4] f32 (validated r2/r3) --
__global__ __launch_bounds__(256) void emb_gemm(
    const bf16* __restrict__ emb_bf, const bf16* __restrict__ Wih0_bf,
    const float* __restrict__ b0, float* __restrict__ E) {
    __shared__ float pb[4 * 128 * 17];
    const int tid = threadIdx.x, l = tid & 63, w = tid >> 6;
    const int lm = l & 15, k8 = (l >> 4) << 3;
    const int colbase = blockIdx.x * 16;
    const int gcol = colbase + lm;
    const int kq = w * 128;

    f32x4_t acc[8];
    #pragma unroll
    for (int rt = 0; rt < 8; ++rt) acc[rt] = f32x4_t{0.f, 0.f, 0.f, 0.f};
    bf16x8_t bf[4];
    #pragma unroll
    for (int k = 0; k < 4; ++k)
        bf[k] = *reinterpret_cast<const bf16x8_t*>(Wih0_bf + gcol * EMBD + kq + k * 32 + k8);
    #pragma unroll
    for (int k = 0; k < 4; ++k)
        #pragma unroll
        for (int rt = 0; rt < 8; ++rt) {
            bf16x8_t a = *reinterpret_cast<const bf16x8_t*>(
                emb_bf + (rt * 16 + lm) * EMBD + kq + k * 32 + k8);
            acc[rt] = __builtin_amdgcn_mfma_f32_16x16x32_bf16(a, bf[k], acc[rt], 0, 0, 0);
        }
    const int r0 = (l >> 4) << 2;
    #pragma unroll
    for (int rt = 0; rt < 8; ++rt)
        #pragma unroll
        for (int r = 0; r < 4; ++r)
            pb[(w * 128 + rt * 16 + r0 + r) * 17 + lm] = acc[rt][r];
    __syncthreads();
    #pragma unroll
    for (int i = 0; i < 8; ++i) {
        int p = tid + i * 256;
        int m = p >> 4, cc = p & 15;
        float g = pb[(0 * 128 + m) * 17 + cc] + pb[(1 * 128 + m) * 17 + cc]
                + pb[(2 * 128 + m) * 17 + cc] + pb[(3 * 128 + m) * 17 + cc];
        E[m * G4 + colbase + cc] = g + b0[colbase + cc];
    }
}

// ---------------- persistent 2-group pipelined LSTM --------------------------
// GRP 0 (wg   0..127): layer0, steps s=0..SEQ-1; reads r0[s], writes r0[s+1]
// GRP 1 (wg 128..255): layer1, steps s=1..SEQ (t=s-1); reads r0[s], r1[s-1], writes r1[s]
template<int GRP, int NKC>
__device__ __forceinline__ void run_layer(
    const int* __restrict__ x,
    const bf16* __restrict__ Wx, const bf16* __restrict__ Wh,
    const float* __restrict__ E, const float* __restrict__ b1,
    const float* __restrict__ c0,
    bf16* __restrict__ rSelf, const bf16* __restrict__ rOther,
    unsigned* __restrict__ cnt, float* __restrict__ out,
    float* __restrict__ pbuf, int tid, int wg)
{
    const int gl = wg & 127;
    const int hb = gl * 8;                       // 8 h-cols per WG
    const int l  = tid & 63, kg = tid >> 6;      // wave = K-slice group
    const int lm = l & 15, lk = l >> 4;

    // gate columns (weight rows): tile nt covers sections 2nt + (lm>>3)
    int gcol[2];
    #pragma unroll
    for (int nt = 0; nt < 2; ++nt)
        gcol[nt] = (2 * nt + (lm >> 3)) * HID + hb + (lm & 7);

    const bf16* W = (GRP == 0) ? Wh : ((kg < 2) ? Wx : Wh);
    const int kbase = (GRP == 0) ? kg * 256 : (kg & 1) * 512;

    // ---- forced register-resident weights (asm can't be sunk/remat'd) ----
    bf16x8_t Breg[2][NKC];
    #pragma unroll
    for (int nt = 0; nt < 2; ++nt)
        #pragma unroll
        for (int kc = 0; kc < NKC; ++kc) {
            const bf16* wp = W + (size_t)gcol[nt] * HID + kbase + kc * 32 + lk * 8;
            asm volatile("global_load_dwordx4 %0, %1, off" : "=v"(Breg[nt][kc]) : "v"(wp));
        }
    asm volatile("s_waitcnt vmcnt(0)" ::: "memory");

    // ---- activation mapping: thread -> (row am, 2 h-cols) ----
    const int am = tid >> 2, cp = tid & 3;
    const int cc0 = cp * 2, col0 = hb + cc0;
    float creg[2];
    creg[0] = c0[GRP * HBS + am * HID + col0];
    creg[1] = c0[GRP * HBS + am * HID + col0 + 1];

    const unsigned* cOwn = cnt + GRP * 8 * CNTS;
    const unsigned* cL0  = cnt;
    unsigned* aOwn = (unsigned*)cOwn;

    const int s_begin = (GRP == 0) ? 0 : 1;
    const int s_end   = (GRP == 0) ? SEQ : SEQ + 1;

    for (int s = s_begin; s < s_end; ++s) {
        // ---- wait phase ----
        if (tid == 0) {
            const unsigned tOwn = (unsigned)(GRP == 0 ? s : s - 1) * 16u;
            const unsigned tL0  = (unsigned)s * 16u;
            for (;;) {
                bool ok = true;
                #pragma unroll
                for (int i = 0; i < 8; ++i)
                    ok &= (__hip_atomic_load(cOwn + i * CNTS, __ATOMIC_RELAXED,
                                             __HIP_MEMORY_SCOPE_AGENT) >= tOwn);
                if (GRP == 1) {
                    #pragma unroll
                    for (int i = 0; i < 8; ++i)
                        ok &= (__hip_atomic_load(cL0 + i * CNTS, __ATOMIC_RELAXED,
                                                 __HIP_MEMORY_SCOPE_AGENT) >= tL0);
                }
                if (ok) break;
                __builtin_amdgcn_s_sleep(2);
            }
        }
        __syncthreads();

        // ---- GEMM: K-slice per wave, cached A reads from ring ----
        const bf16* asrc;
        if (GRP == 0) asrc = rSelf + (size_t)s * HBS;
        else          asrc = (kg < 2) ? (rOther + (size_t)s * HBS)
                                      : (rSelf + (size_t)(s - 1) * HBS);

        f32x4_t acc[4][2];
        #pragma unroll
        for (int mt = 0; mt < 4; ++mt)
            #pragma unroll
            for (int nt = 0; nt < 2; ++nt) acc[mt][nt] = f32x4_t{0.f, 0.f, 0.f, 0.f};

        #pragma unroll
        for (int kc = 0; kc < NKC; ++kc) {
            bf16x8_t a[4];
            #pragma unroll
            for (int mt = 0; mt < 4; ++mt)
                a[mt] = *reinterpret_cast<const bf16x8_t*>(
                    asrc + (size_t)(mt * 16 + lm) * HID + kbase + kc * 32 + lk * 8);
            #pragma unroll
            for (int mt = 0; mt < 4; ++mt)
                #pragma unroll
                for (int nt = 0; nt < 2; ++nt)
                    acc[mt][nt] = __builtin_amdgcn_mfma_f32_16x16x32_bf16(
                        a[mt], Breg[nt][kc], acc[mt][nt], 0, 0, 0);
        }

        // ---- partials -> LDS [wave][m][c] (pad 36: 2-way max) ----
        #pragma unroll
        for (int mt = 0; mt < 4; ++mt)
            #pragma unroll
            for (int nt = 0; nt < 2; ++nt)
                #pragma unroll
                for (int r = 0; r < 4; ++r)
                    pbuf[(kg * 64 + mt * 16 + lk * 4 + r) * 36 + nt * 16 + lm]
                        = acc[mt][nt][r];
        __syncthreads();

        // ---- gate assembly + activation + ring write ----
        float g[4][2];
        #pragma unroll
        for (int sec = 0; sec < 4; ++sec) { g[sec][0] = 0.f; g[sec][1] = 0.f; }
        #pragma unroll
        for (int w4 = 0; w4 < 4; ++w4)
            #pragma unroll
            for (int sec = 0; sec < 4; ++sec) {
                const float* pp = &pbuf[(w4 * 64 + am) * 36 + sec * 8 + cc0];
                g[sec][0] += pp[0];
                g[sec][1] += pp[1];
            }
        if (GRP == 0) {
            const int xv = x[s * BATCH + am];
            const float* Ep = E + (size_t)xv * G4 + col0;
            #pragma unroll
            for (int sec = 0; sec < 4; ++sec) {
                g[sec][0] += Ep[sec * HID];
                g[sec][1] += Ep[sec * HID + 1];
            }
        } else {
            #pragma unroll
            for (int sec = 0; sec < 4; ++sec) {
                g[sec][0] += b1[sec * HID + col0];
                g[sec][1] += b1[sec * HID + col0 + 1];
            }
        }

        float hn[2];
        #pragma unroll
        for (int j = 0; j < 2; ++j) {
            float si = sigm(g[0][j]);
            float sf = sigm(g[1][j]);
            float tg = tanhf(g[2][j]);
            float so = sigm(g[3][j]);
            float cn = sf * creg[j] + si * tg;
            hn[j] = so * tanhf(cn);
            creg[j] = cn;
        }
        unsigned short u0 = __builtin_bit_cast(unsigned short, __float2bfloat16(hn[0]));
        unsigned short u1 = __builtin_bit_cast(unsigned short, __float2bfloat16(hn[1]));
        const int wslot = (GRP == 0) ? s + 1 : s;
        cstore4(rSelf + (size_t)wslot * HBS + am * HID + col0,
                (unsigned)u0 | ((unsigned)u1 << 16));

        const bool last = (GRP == 0) ? (s == SEQ - 1) : (s == SEQ);
        if (last) {
            float* oh = out + BATCH * VOCAB + GRP * HBS;
            float* oc = out + BATCH * VOCAB + 2 * HBS + GRP * HBS;
            oh[am * HID + col0]     = hn[0];
            oh[am * HID + col0 + 1] = hn[1];
            oc[am * HID + col0]     = creg[0];
            oc[am * HID + col0 + 1] = creg[1];
        }

        // ---- arrive phase ----
        asm volatile("s_waitcnt vmcnt(0)" ::: "memory");
        __syncthreads();
        if (tid == 0)
            __hip_atomic_fetch_add(aOwn + (wg & 7) * CNTS, 1u,
                                   __ATOMIC_RELAXED, __HIP_MEMORY_SCOPE_AGENT);
    }
}

__global__ __launch_bounds__(256, 1) void lstm_persist(
    const int* __restrict__ x,
    const bf16* __restrict__ Whh0, const bf16* __restrict__ Wih1,
    const bf16* __restrict__ Whh1,
    const float* __restrict__ E, const float* __restrict__ b1,
    const float* __restrict__ c0,
    bf16* __restrict__ r0, bf16* __restrict__ r1,
    unsigned* __restrict__ cnt, float* __restrict__ out)
{
    __shared__ float pbuf[4 * 64 * 36];   // 36 KB
    const int tid = threadIdx.x, wg = blockIdx.x;
    if (wg < 128)
        run_layer<0, 8>(x, nullptr, Whh0, E, nullptr, c0, r0, nullptr, cnt, out, pbuf, tid, wg);
    else
        run_layer<1, 16>(x, Wih1, Whh1, E, b1, c0, r1, r0, cnt, out, pbuf, tid, wg);
}

// ---------------- FC head ----------------
__global__ void logits_kernel(const float* __restrict__ h, const float* __restrict__ Wfc,
                              const float* __restrict__ bfc, float* __restrict__ out) {
    int t = blockIdx.x * blockDim.x + threadIdx.x;
    if (t >= BATCH * VOCAB) return;
    int m = t >> 7, v = t & 127;
    const float4* hp = reinterpret_cast<const float4*>(h + (size_t)m * HID);
    const float4* wp = reinterpret_cast<const float4*>(Wfc + (size_t)v * HID);
    float acc = 0.f;
    #pragma unroll 4
    for (int k = 0; k < HID / 4; ++k) {
        float4 a = hp[k], w = wp[k];
        acc += a.x * w.x + a.y * w.y + a.z * w.z + a.w * w.w;
    }
    out[t] = acc + bfc[v];
}

// ---------------- launch ----------------
extern "C" void kernel_launch(void* const* d_in, const int* in_sizes, int n_in,
                              void* d_out, int out_size, void* d_ws, size_t ws_size,
                              hipStream_t stream) {
    const int*   x    = (const int*)d_in[0];
    const float* h0   = (const float*)d_in[1];
    const float* c0   = (const float*)d_in[2];
    const float* emb  = (const float*)d_in[3];
    const float* Wih0 = (const float*)d_in[4];
    const float* Whh0 = (const float*)d_in[5];
    const float* b0   = (const float*)d_in[6];
    const float* Wih1 = (const float*)d_in[7];
    const float* Whh1 = (const float*)d_in[8];
    const float* b1   = (const float*)d_in[9];
    const float* Wfc  = (const float*)d_in[10];
    const float* bfc  = (const float*)d_in[11];
    float* out = (float*)d_out;

    char* ws = (char*)d_ws;
    size_t off = 0;
    auto alloc = [&](size_t bytes) -> void* {
        void* p = ws + off;
        off += (bytes + 255) & ~(size_t)255;
        return p;
    };
    bf16*  Whh0_bf = (bf16*)alloc((size_t)G4 * HID * 2);
    bf16*  Wih1_bf = (bf16*)alloc((size_t)G4 * HID * 2);
    bf16*  Whh1_bf = (bf16*)alloc((size_t)G4 * HID * 2);
    float* E       = (float*)alloc((size_t)VOCAB * G4 * 4);
    bf16*  r0      = (bf16*)alloc((size_t)(SEQ + 1) * HBS * 2);   // 32.9 MB ring
    bf16*  r1      = (bf16*)alloc((size_t)(SEQ + 1) * HBS * 2);   // 32.9 MB ring
    unsigned* cnt  = (unsigned*)alloc(16 * CNTS * 4);
    (void)ws_size; (void)in_sizes; (void)n_in; (void)out_size;

    // precompute-only buffers overlaid on ring slots 1.. (consumed before
    // persist writes those slots; stream order guarantees safety)
    bf16* Wih0_bf = (bf16*)(r0 + HBS);     // 4 MB in r0 slots 1..33
    bf16* emb_bf  = (bf16*)(r1 + HBS);     // 128 KB in r1 slot 1

    cast_f32_bf16<<<64,  256, 0, stream>>>(emb,  emb_bf,  VOCAB * EMBD);
    cast_f32_bf16<<<512, 256, 0, stream>>>(Wih0, Wih0_bf, G4 * EMBD);
    cast_f32_bf16<<<512, 256, 0, stream>>>(Whh0, Whh0_bf, G4 * HID);
    cast_f32_bf16<<<512, 256, 0, stream>>>(Wih1, Wih1_bf, G4 * HID);
    cast_f32_bf16<<<512, 256, 0, stream>>>(Whh1, Whh1_bf, G4 * HID);
    init_all<<<64, 256, 0, stream>>>(h0, r0, r1, cnt);
    emb_gemm<<<G4 / 16, 256, 0, stream>>>(emb_bf, Wih0_bf, b0, E);

    lstm_persist<<<256, 256, 0, stream>>>(x, Whh0_bf, Wih1_bf, Whh1_bf,
                                          E, b1, c0, r0, r1, cnt, out);

    logits_kernel<<<(BATCH * VOCAB + 255) / 256, 256, 0, stream>>>(
        out + BATCH * VOCAB + HBS, Wfc, bfc, out);
}